// Round 3
// baseline (376.086 us; speedup 1.0000x reference)
//
#include <hip/hip_runtime.h>
#include <stdint.h>

// Problem: B=1024, T=65, D=H=512. Only the SLOW critic feeds the output
// (the normal critic is dead code in the reference). Pipeline:
//   prep:  W1s,W2s (512x512 f32) -> bf16 transposed Wt[n][k]; zero tarval
//   gemm1: H1 = silu(feat @ W1s + b1s)        (66560x512, bf16 out)
//   gemm2: tarval[row] = silu(H1 @ W2s + b2s) @ W3s   (fused, atomic reduce)
//   scan:  tarval -> lambda-return reverse scan -> out (f32!)

#define MROWS 66560   // 1024*65
#define RBLK 520      // MROWS/128
#define LAMF 0.95f
#define DISCF ((float)(1.0 - 1.0 / 333.0))

typedef __attribute__((ext_vector_type(8))) __bf16 bf16x8;
typedef __attribute__((ext_vector_type(4))) float f32x4;
typedef __attribute__((ext_vector_type(4))) unsigned int u32x4;

__device__ __forceinline__ unsigned short f2bf(float f) {
  unsigned int u = __float_as_uint(f);
  return (unsigned short)((u + 0x7FFFu + ((u >> 16) & 1u)) >> 16);
}
__device__ __forceinline__ float silu_f(float x) { return x / (1.0f + __expf(-x)); }

// size arg must be a LITERAL constant (not template-dependent)
__device__ __forceinline__ void gload_lds16(const void* g, void* l) {
  __builtin_amdgcn_global_load_lds(
      (const __attribute__((address_space(1))) void*)g,
      (__attribute__((address_space(3))) void*)l, 16, 0, 0);
}

// ---------------- prep: weight transpose+convert, zero tarval ----------------
__global__ __launch_bounds__(256) void prep_kernel(
    const float* __restrict__ W1, const float* __restrict__ W2,
    unsigned short* __restrict__ Wt1, unsigned short* __restrict__ Wt2,
    float* __restrict__ tarval) {
  int id = blockIdx.x * 256 + threadIdx.x;   // 0..262143
  int n = id >> 9, k = id & 511;
  Wt1[id] = f2bf(W1[k * 512 + n]);           // Wt[n][k] = W[k][n]
  Wt2[id] = f2bf(W2[k * 512 + n]);
  if (id < MROWS) tarval[id] = 0.0f;
}

// XCD-aware tile mapping: the 4 col-blocks sharing one A row-tile are
// consecutive in per-XCD dispatch order -> A tile stays in that XCD's L2.
__device__ __forceinline__ void tile_map(int bid, int& rb, int& cb) {
  int xcd = bid & 7;
  int idx = bid >> 3;        // 0..259 per XCD
  rb = xcd * 65 + (idx >> 2);
  cb = idx & 3;
}

// ---------------- GEMM1: A=feat f32 (reg-staged converting), B=Wt1 bf16 -----
__global__ __launch_bounds__(256) void gemm1_kernel(
    const float* __restrict__ A, const unsigned short* __restrict__ Bt,
    const float* __restrict__ bias, unsigned short* __restrict__ Hout) {
  __shared__ __align__(16) unsigned char lds[2 * 128 * 64 * 2];  // 32 KB
  unsigned char* Alds = lds;
  unsigned char* Blds = lds + 128 * 64 * 2;

  int rb, cb; tile_map(blockIdx.x, rb, cb);
  const int m0 = rb * 128, n0 = cb * 128;
  const int tid = threadIdx.x;
  const int lane = tid & 63, w = tid >> 6;
  const int wr = w >> 1, wc = w & 1;

  f32x4 acc[4][4] = {};

  for (int ks = 0; ks < 512; ks += 64) {
    // B stage via global_load_lds (linear LDS, per-lane source)
    {
      const int base = w * 1024;
#pragma unroll
      for (int i = 0; i < 4; ++i) {
        int L = i * 4096 + base + lane * 16;
        int row = L >> 7, kb = L & 127;
        gload_lds16((const void*)(Bt + (size_t)(n0 + row) * 512 + ks + (kb >> 1)),
                    (void*)(Blds + i * 4096 + base));
      }
    }
    // A stage: load f32, convert to bf16, ds_write
#pragma unroll
    for (int i = 0; i < 4; ++i) {
      int L = (i * 256 + tid) * 16;
      int row = L >> 7, kb = L & 127;
      const float* src = A + (size_t)(m0 + row) * 512 + ks + (kb >> 1);
      f32x4 v0 = *(const f32x4*)(src);
      f32x4 v1 = *(const f32x4*)(src + 4);
      union { unsigned short h[8]; u32x4 u; } p;
      p.h[0] = f2bf(v0[0]); p.h[1] = f2bf(v0[1]); p.h[2] = f2bf(v0[2]); p.h[3] = f2bf(v0[3]);
      p.h[4] = f2bf(v1[0]); p.h[5] = f2bf(v1[1]); p.h[6] = f2bf(v1[2]); p.h[7] = f2bf(v1[3]);
      *(u32x4*)(Alds + L) = p.u;
    }
    __syncthreads();
#pragma unroll
    for (int kk = 0; kk < 2; ++kk) {
      bf16x8 af[4], bf[4];
      const int kbyte = kk * 64 + ((lane >> 4) * 16);
#pragma unroll
      for (int m = 0; m < 4; ++m)
        af[m] = *(const bf16x8*)(Alds + (wr * 64 + m * 16 + (lane & 15)) * 128 + kbyte);
#pragma unroll
      for (int n = 0; n < 4; ++n)
        bf[n] = *(const bf16x8*)(Blds + (wc * 64 + n * 16 + (lane & 15)) * 128 + kbyte);
#pragma unroll
      for (int m = 0; m < 4; ++m)
#pragma unroll
        for (int n = 0; n < 4; ++n)
          acc[m][n] = __builtin_amdgcn_mfma_f32_16x16x32_bf16(af[m], bf[n], acc[m][n], 0, 0, 0);
    }
    __syncthreads();
  }
  // epilogue: bias + silu -> bf16 H1
#pragma unroll
  for (int n = 0; n < 4; ++n) {
    const int col = n0 + wc * 64 + n * 16 + (lane & 15);
    const float bn = bias[col];
#pragma unroll
    for (int m = 0; m < 4; ++m) {
      const int rbase = m0 + wr * 64 + m * 16 + (lane >> 4) * 4;
#pragma unroll
      for (int i = 0; i < 4; ++i)
        Hout[(size_t)(rbase + i) * 512 + col] = f2bf(silu_f(acc[m][n][i] + bn));
    }
  }
}

// ---------------- GEMM2: A=H1 bf16, B=Wt2 bf16, fused W3 reduction ----------
__global__ __launch_bounds__(256) void gemm2_kernel(
    const unsigned short* __restrict__ A, const unsigned short* __restrict__ Bt,
    const float* __restrict__ bias, const float* __restrict__ W3,
    float* __restrict__ tarval) {
  __shared__ __align__(16) unsigned char lds[2 * 128 * 64 * 2];  // 32 KB
  unsigned char* Alds = lds;
  unsigned char* Blds = lds + 128 * 64 * 2;

  int rb, cb; tile_map(blockIdx.x, rb, cb);
  const int m0 = rb * 128, n0 = cb * 128;
  const int tid = threadIdx.x;
  const int lane = tid & 63, w = tid >> 6;
  const int wr = w >> 1, wc = w & 1;

  f32x4 acc[4][4] = {};

  for (int ks = 0; ks < 512; ks += 64) {
    const int base = w * 1024;
#pragma unroll
    for (int i = 0; i < 4; ++i) {
      int L = i * 4096 + base + lane * 16;
      int row = L >> 7, kb = L & 127;
      gload_lds16((const void*)(A + (size_t)(m0 + row) * 512 + ks + (kb >> 1)),
                  (void*)(Alds + i * 4096 + base));
    }
#pragma unroll
    for (int i = 0; i < 4; ++i) {
      int L = i * 4096 + base + lane * 16;
      int row = L >> 7, kb = L & 127;
      gload_lds16((const void*)(Bt + (size_t)(n0 + row) * 512 + ks + (kb >> 1)),
                  (void*)(Blds + i * 4096 + base));
    }
    __syncthreads();
#pragma unroll
    for (int kk = 0; kk < 2; ++kk) {
      bf16x8 af[4], bf[4];
      const int kbyte = kk * 64 + ((lane >> 4) * 16);
#pragma unroll
      for (int m = 0; m < 4; ++m)
        af[m] = *(const bf16x8*)(Alds + (wr * 64 + m * 16 + (lane & 15)) * 128 + kbyte);
#pragma unroll
      for (int n = 0; n < 4; ++n)
        bf[n] = *(const bf16x8*)(Blds + (wc * 64 + n * 16 + (lane & 15)) * 128 + kbyte);
#pragma unroll
      for (int m = 0; m < 4; ++m)
#pragma unroll
        for (int n = 0; n < 4; ++n)
          acc[m][n] = __builtin_amdgcn_mfma_f32_16x16x32_bf16(af[m], bf[n], acc[m][n], 0, 0, 0);
    }
    __syncthreads();
  }
  // epilogue: silu(acc+b2) * W3[col], reduce over this wave's 64 cols, atomic
#pragma unroll
  for (int m = 0; m < 4; ++m) {
    float ps0 = 0.f, ps1 = 0.f, ps2 = 0.f, ps3 = 0.f;
#pragma unroll
    for (int n = 0; n < 4; ++n) {
      const int col = n0 + wc * 64 + n * 16 + (lane & 15);
      const float bn = bias[col];
      const float w3 = W3[col];
      ps0 += silu_f(acc[m][n][0] + bn) * w3;
      ps1 += silu_f(acc[m][n][1] + bn) * w3;
      ps2 += silu_f(acc[m][n][2] + bn) * w3;
      ps3 += silu_f(acc[m][n][3] + bn) * w3;
    }
    float ps[4] = {ps0, ps1, ps2, ps3};
#pragma unroll
    for (int i = 0; i < 4; ++i) {
      float v = ps[i];
      v += __shfl_xor(v, 1);
      v += __shfl_xor(v, 2);
      v += __shfl_xor(v, 4);
      v += __shfl_xor(v, 8);
      if ((lane & 15) == 0) {
        int row = m0 + wr * 64 + m * 16 + (lane >> 4) * 4 + i;
        atomicAdd(&tarval[row], v);
      }
    }
  }
}

// ---------------- scan: lambda-return reverse scan per batch row ------------
__global__ __launch_bounds__(64) void scan_kernel(
    const float* __restrict__ tarval, const float* __restrict__ reward,
    const float* __restrict__ cont, const float* __restrict__ voffset,
    const float* __restrict__ vscale, const float* __restrict__ b3,
    float* __restrict__ out) {
  __shared__ float tv[64];
  __shared__ float ret[64];
  const int b = blockIdx.x, t = threadIdx.x;  // t = 0..63 maps to orig t+1
  tv[t] = (tarval[b * 65 + 1 + t] + b3[0]) * vscale[0] + voffset[0];
  __syncthreads();
  if (t == 0) {
    float carry = tv[63];  // boot = tarval[:, -1]
    for (int j = 63; j >= 0; --j) {
      const int tt = j + 1;
      const float disc = cont[b * 65 + tt] * DISCF;
      const float r = reward[b * 65 + tt] + disc * ((1.0f - LAMF) * tv[j] + LAMF * carry);
      ret[j] = r;
      carry = r;
    }
  }
  __syncthreads();
  out[b * 64 + t] = ret[t];   // f32 output (reference returns float32)
}

extern "C" void kernel_launch(void* const* d_in, const int* in_sizes, int n_in,
                              void* d_out, int out_size, void* d_ws, size_t ws_size,
                              hipStream_t stream) {
  const float* feat    = (const float*)d_in[0];
  const float* reward  = (const float*)d_in[1];
  const float* cont    = (const float*)d_in[2];
  const float* voffset = (const float*)d_in[3];
  const float* vscale  = (const float*)d_in[4];
  // slow critic weights (the normal critic is dead code)
  const float* W1s = (const float*)d_in[11];
  const float* b1s = (const float*)d_in[12];
  const float* W2s = (const float*)d_in[13];
  const float* b2s = (const float*)d_in[14];
  const float* W3s = (const float*)d_in[15];
  const float* b3s = (const float*)d_in[16];

  char* ws = (char*)d_ws;
  unsigned short* Wt1 = (unsigned short*)ws;                   // 512 KB
  unsigned short* Wt2 = (unsigned short*)(ws + (512u << 10));  // 512 KB
  float* tarval       = (float*)(ws + (1024u << 10));          // 266 240 B
  unsigned short* H1  = (unsigned short*)(ws + (2048u << 10)); // 68 157 440 B

  prep_kernel<<<1024, 256, 0, stream>>>(W1s, W2s, Wt1, Wt2, tarval);
  gemm1_kernel<<<RBLK * 4, 256, 0, stream>>>(feat, Wt1, b1s, H1);
  gemm2_kernel<<<RBLK * 4, 256, 0, stream>>>(H1, Wt2, b2s, W3s, tarval);
  scan_kernel<<<1024, 64, 0, stream>>>(tarval, reward, cont, voffset, vscale, b3s,
                                       (float*)d_out);
}